// Round 2
// baseline (192.048 us; speedup 1.0000x reference)
//
#include <hip/hip_runtime.h>
#include <math.h>

#ifndef __has_builtin
#define __has_builtin(x) 0
#endif

__device__ __forceinline__ float fast_fract(float x) {
#if __has_builtin(__builtin_amdgcn_fractf)
    return __builtin_amdgcn_fractf(x);
#else
    return x - floorf(x);
#endif
}
// cos(2*pi*x) for x in [0,1)
__device__ __forceinline__ float fast_cos2pi(float x) {
#if __has_builtin(__builtin_amdgcn_cosf)
    return __builtin_amdgcn_cosf(x);
#else
    return cosf(x * 6.28318530717958647692f);
#endif
}
__device__ __forceinline__ float fast_exp2(float x) {
#if __has_builtin(__builtin_amdgcn_exp2f)
    return __builtin_amdgcn_exp2f(x);
#else
    return exp2f(x);
#endif
}

constexpr int kN = 16384, kD = 8, kS = 8, kF = 1024, kR = 2048;
constexpr int kNloc = 64;               // n per block
constexpr int kRchunk = kR / kS;        // 256 r per wave

__global__ __launch_bounds__(512, 2)
void pathwise_kernel(const float* __restrict__ X,      // [N,8]
                     const float* __restrict__ Z,      // [R,8]
                     const float* __restrict__ omega,  // [S,8,F]
                     const float* __restrict__ phase,  // [S,F]
                     const float* __restrict__ fw,     // [S,F]
                     const float* __restrict__ cw,     // [S,R]
                     const float* __restrict__ varp,
                     const float* __restrict__ lsp,
                     float* __restrict__ out)          // [S,N]
{
    const int tid  = threadIdx.x;
    const int nloc = tid & 63;
    // wave-uniform s index; readfirstlane so the compiler provably scalarizes
    // all omega/phase/fw/cw/Z addressing (s_load GEMV pattern).
    const int sc   = __builtin_amdgcn_readfirstlane(tid >> 6);
    const int n    = blockIdx.x * kNloc + nloc;

    const float variance = varp[0];
    const float ls       = lsp[0];
    const float inv_ls   = 1.0f / ls;
    const float invls2   = inv_ls * inv_ls;
    constexpr float inv2pi = 0.15915494309189535f;
    constexpr float log2e  = 1.4426950408889634f;
    const float scale = sqrtf(2.0f * variance / (float)kF);
    const float L = log2e * invls2;     // base-2 exponent scale

    __shared__ float zt_lds[kR];               // -0.5*L*||z_r||^2
    __shared__ float red[kS][kNloc][kS + 1];   // +1 pad: conflict-free transpose

    // per-thread x
    float x[kD];
    {
        const float4 x0 = *reinterpret_cast<const float4*>(X + n * kD);
        const float4 x1 = *reinterpret_cast<const float4*>(X + n * kD + 4);
        x[0]=x0.x; x[1]=x0.y; x[2]=x0.z; x[3]=x0.w;
        x[4]=x1.x; x[5]=x1.y; x[6]=x1.z; x[7]=x1.w;
    }

    // precompute z-term into LDS (4 iters, coalesced float4 loads)
    for (int r = tid; r < kR; r += 512) {
        const float4 z0 = *reinterpret_cast<const float4*>(Z + r * kD);
        const float4 z1 = *reinterpret_cast<const float4*>(Z + r * kD + 4);
        float z2 = z0.x*z0.x + z0.y*z0.y + z0.z*z0.z + z0.w*z0.w
                 + z1.x*z1.x + z1.y*z1.y + z1.z*z1.z + z1.w*z1.w;
        zt_lds[r] = -0.5f * L * z2;
    }
    __syncthreads();

    // ---- Part A: RFF prior for s = sc ------------------------------------
    float xa[kD];
    #pragma unroll
    for (int d = 0; d < kD; ++d) xa[d] = x[d] * inv_ls * inv2pi;
    const float* __restrict__ om  = omega + sc * (kD * kF);
    const float* __restrict__ ph  = phase + sc * kF;
    const float* __restrict__ fwp = fw    + sc * kF;

    float accA = 0.f;
    #pragma unroll 4
    for (int f = 0; f < kF; ++f) {
        float th = ph[f] * inv2pi;                 // theta in revolutions
        #pragma unroll
        for (int d = 0; d < kD; ++d)
            th = fmaf(xa[d], om[d * kF + f], th);  // v_fmac, sgpr omega operand
        accA = fmaf(fwp[f], fast_cos2pi(fast_fract(th)), accA);
    }

    // ---- Part B: kernel-correction partial over r-chunk sc, all 8 s ------
    float xb[kD]; float x2 = 0.f;
    #pragma unroll
    for (int d = 0; d < kD; ++d) { xb[d] = x[d] * L; x2 = fmaf(x[d], x[d], x2); }
    const float xt = -0.5f * L * x2;

    float accU[kS];
    #pragma unroll
    for (int j = 0; j < kS; ++j) accU[j] = 0.f;

    const int r0 = sc * kRchunk;
    #pragma unroll 2
    for (int rr = 0; rr < kRchunk; ++rr) {
        const int r = r0 + rr;
        float e = xt + zt_lds[r];
        #pragma unroll
        for (int d = 0; d < kD; ++d)
            e = fmaf(xb[d], Z[r * kD + d], e);     // L*(x.z), sgpr z operand
        e = fminf(e, 0.f);                          // == max(sq, 0) clamp
        const float K = fast_exp2(e);               // exp(-0.5*sq/ls^2), base-2
        #pragma unroll
        for (int j = 0; j < kS; ++j)
            accU[j] = fmaf(K, cw[j * kR + r], accU[j]);  // sgpr cw operand
    }

    // ---- LDS transpose-reduce of the 8 r-chunk partials ------------------
    #pragma unroll
    for (int j = 0; j < kS; ++j) red[sc][nloc][j] = accU[j];
    __syncthreads();

    float tot = 0.f;
    #pragma unroll
    for (int k = 0; k < kS; ++k) tot += red[k][nloc][sc];

    out[sc * kN + n] = fmaf(variance, tot, scale * accA);
}

extern "C" void kernel_launch(void* const* d_in, const int* in_sizes, int n_in,
                              void* d_out, int out_size, void* d_ws, size_t ws_size,
                              hipStream_t stream) {
    const float* X  = (const float*)d_in[0];
    const float* Z  = (const float*)d_in[1];
    const float* om = (const float*)d_in[2];
    const float* ph = (const float*)d_in[3];
    const float* fw = (const float*)d_in[4];
    const float* cw = (const float*)d_in[5];
    const float* vp = (const float*)d_in[6];
    const float* lp = (const float*)d_in[7];
    float* out = (float*)d_out;

    dim3 grid(kN / kNloc);   // 256 blocks
    dim3 block(512);
    hipLaunchKernelGGL(pathwise_kernel, grid, block, 0, stream,
                       X, Z, om, ph, fw, cw, vp, lp, out);
}

// Round 3
// 136.986 us; speedup vs baseline: 1.4020x; 1.4020x over previous
//
#include <hip/hip_runtime.h>
#include <math.h>

#ifndef __has_builtin
#define __has_builtin(x) 0
#endif

__device__ __forceinline__ float fast_fract(float x) {
#if __has_builtin(__builtin_amdgcn_fractf)
    return __builtin_amdgcn_fractf(x);
#else
    return x - floorf(x);
#endif
}
// cos(2*pi*x)
__device__ __forceinline__ float fast_cos2pi(float x) {
#if __has_builtin(__builtin_amdgcn_cosf)
    return __builtin_amdgcn_cosf(x);
#else
    return cosf(x * 6.28318530717958647692f);
#endif
}
__device__ __forceinline__ float fast_exp2(float x) {
#if __has_builtin(__builtin_amdgcn_exp2f)
    return __builtin_amdgcn_exp2f(x);
#else
    return exp2f(x);
#endif
}

constexpr int kN = 16384, kD = 8, kS = 8, kF = 1024, kR = 2048;

// ===========================================================================
// Kernel A: RFF prior.  grid (N/64, S), 512 threads = 8 waves.
// Wave w handles f-chunk [w*128, (w+1)*128); lanes = 64 n values.
// 8 independent theta chains per iteration for ILP; omega/phase/fw operands
// are wave-uniform -> SGPR loads.
// ===========================================================================
__global__ __launch_bounds__(512, 8)
void prior_kernel(const float* __restrict__ X,      // [N,8]
                  const float* __restrict__ omega,  // [S,8,F]
                  const float* __restrict__ phase,  // [S,F]
                  const float* __restrict__ fw,     // [S,F]
                  const float* __restrict__ varp,
                  const float* __restrict__ lsp,
                  float* __restrict__ out)          // [S,N]
{
    const int tid  = threadIdx.x;
    const int nloc = tid & 63;
    const int wave = __builtin_amdgcn_readfirstlane(tid >> 6);
    const int s    = blockIdx.y;
    const int n    = blockIdx.x * 64 + nloc;

    const float variance = varp[0];
    const float inv_ls   = 1.0f / lsp[0];
    constexpr float inv2pi = 0.15915494309189535f;
    const float scale = sqrtf(2.0f * variance / (float)kF);

    float xa[kD];
    {
        const float4 x0 = *reinterpret_cast<const float4*>(X + n * kD);
        const float4 x1 = *reinterpret_cast<const float4*>(X + n * kD + 4);
        const float m = inv_ls * inv2pi;
        xa[0]=x0.x*m; xa[1]=x0.y*m; xa[2]=x0.z*m; xa[3]=x0.w*m;
        xa[4]=x1.x*m; xa[5]=x1.y*m; xa[6]=x1.z*m; xa[7]=x1.w*m;
    }

    const float* __restrict__ om  = omega + s * (kD * kF);
    const float* __restrict__ ph  = phase + s * kF;
    const float* __restrict__ fwp = fw    + s * kF;

    const int f0 = wave * 128;
    float acc0 = 0.f, acc1 = 0.f;

    for (int fb = f0; fb < f0 + 128; fb += 8) {
        float c[8];
        #pragma unroll
        for (int j = 0; j < 8; ++j) {
            float t = ph[fb + j] * inv2pi;
            #pragma unroll
            for (int d = 0; d < kD; ++d)
                t = fmaf(xa[d], om[d * kF + fb + j], t);
            c[j] = fast_cos2pi(fast_fract(t));
        }
        #pragma unroll
        for (int j = 0; j < 8; j += 2) {
            acc0 = fmaf(fwp[fb + j],     c[j],     acc0);
            acc1 = fmaf(fwp[fb + j + 1], c[j + 1], acc1);
        }
    }

    __shared__ float red[8][64];
    red[wave][nloc] = acc0 + acc1;
    __syncthreads();

    if (tid < 64) {
        float t = 0.f;
        #pragma unroll
        for (int k = 0; k < 8; ++k) t += red[k][tid];
        out[s * kN + blockIdx.x * 64 + tid] = scale * t;
    }
}

// ===========================================================================
// Kernel B: RBF kernel correction.  grid (N/64), 1024 threads = 16 waves.
// Wave w handles r-chunk [w*128, (w+1)*128); lanes = 64 n values.
// exp computed ONCE per (n,r), shared across all 8 s.  out += result.
// ===========================================================================
__global__ __launch_bounds__(1024, 8)
void update_kernel(const float* __restrict__ X,   // [N,8]
                   const float* __restrict__ Z,   // [R,8]
                   const float* __restrict__ cw,  // [S,R]
                   const float* __restrict__ varp,
                   const float* __restrict__ lsp,
                   float* __restrict__ out)       // [S,N]
{
    const int tid  = threadIdx.x;
    const int nloc = tid & 63;
    const int wave = __builtin_amdgcn_readfirstlane(tid >> 6);
    const int n    = blockIdx.x * 64 + nloc;

    const float variance = varp[0];
    const float inv_ls   = 1.0f / lsp[0];
    constexpr float log2e = 1.4426950408889634f;
    const float L = log2e * inv_ls * inv_ls;

    __shared__ float zt_lds[kR];            // -0.5*L*||z_r||^2
    __shared__ float red[16][64][kS + 1];   // stride 9 -> conflict-free

    float x[kD];
    {
        const float4 x0 = *reinterpret_cast<const float4*>(X + n * kD);
        const float4 x1 = *reinterpret_cast<const float4*>(X + n * kD + 4);
        x[0]=x0.x; x[1]=x0.y; x[2]=x0.z; x[3]=x0.w;
        x[4]=x1.x; x[5]=x1.y; x[6]=x1.z; x[7]=x1.w;
    }

    for (int r = tid; r < kR; r += 1024) {
        const float4 z0 = *reinterpret_cast<const float4*>(Z + r * kD);
        const float4 z1 = *reinterpret_cast<const float4*>(Z + r * kD + 4);
        float z2 = z0.x*z0.x + z0.y*z0.y + z0.z*z0.z + z0.w*z0.w
                 + z1.x*z1.x + z1.y*z1.y + z1.z*z1.z + z1.w*z1.w;
        zt_lds[r] = -0.5f * L * z2;
    }
    __syncthreads();

    float xb[kD]; float x2 = 0.f;
    #pragma unroll
    for (int d = 0; d < kD; ++d) { xb[d] = x[d] * L; x2 = fmaf(x[d], x[d], x2); }
    const float xt = -0.5f * L * x2;

    float accU[2][kS];
    #pragma unroll
    for (int j = 0; j < kS; ++j) { accU[0][j] = 0.f; accU[1][j] = 0.f; }

    const int r0 = wave * 128;
    #pragma unroll 4
    for (int rr = 0; rr < 128; ++rr) {
        const int r = r0 + rr;
        float e = xt + zt_lds[r];
        #pragma unroll
        for (int d = 0; d < kD; ++d)
            e = fmaf(xb[d], Z[r * kD + d], e);   // SGPR z operand
        e = fminf(e, 0.f);
        const float K = fast_exp2(e);
        #pragma unroll
        for (int j = 0; j < kS; ++j)
            accU[rr & 1][j] = fmaf(K, cw[j * kR + r], accU[rr & 1][j]);
    }

    #pragma unroll
    for (int j = 0; j < kS; ++j) red[wave][nloc][j] = accU[0][j] + accU[1][j];
    __syncthreads();

    if (tid < 512) {
        const int n2 = tid & 63;
        const int jj = tid >> 6;   // wave-uniform s index
        float tot = 0.f;
        #pragma unroll
        for (int k = 0; k < 16; ++k) tot += red[k][n2][jj];
        const int idx = jj * kN + blockIdx.x * 64 + n2;
        out[idx] = fmaf(variance, tot, out[idx]);
    }
}

extern "C" void kernel_launch(void* const* d_in, const int* in_sizes, int n_in,
                              void* d_out, int out_size, void* d_ws, size_t ws_size,
                              hipStream_t stream) {
    const float* X  = (const float*)d_in[0];
    const float* Z  = (const float*)d_in[1];
    const float* om = (const float*)d_in[2];
    const float* ph = (const float*)d_in[3];
    const float* fw = (const float*)d_in[4];
    const float* cw = (const float*)d_in[5];
    const float* vp = (const float*)d_in[6];
    const float* lp = (const float*)d_in[7];
    float* out = (float*)d_out;

    hipLaunchKernelGGL(prior_kernel, dim3(kN / 64, kS), dim3(512), 0, stream,
                       X, om, ph, fw, vp, lp, out);
    hipLaunchKernelGGL(update_kernel, dim3(kN / 64), dim3(1024), 0, stream,
                       X, Z, cw, vp, lp, out);
}

// Round 5
// 122.961 us; speedup vs baseline: 1.5619x; 1.1141x over previous
//
#include <hip/hip_runtime.h>
#include <math.h>

#ifndef __has_builtin
#define __has_builtin(x) 0
#endif

typedef __attribute__((ext_vector_type(8))) short bf16x8;
typedef __attribute__((ext_vector_type(4))) float f32x4;

__device__ __forceinline__ float fast_fract(float x) {
#if __has_builtin(__builtin_amdgcn_fractf)
    return __builtin_amdgcn_fractf(x);
#else
    return x - floorf(x);
#endif
}
__device__ __forceinline__ float fast_cos2pi(float x) {   // cos(2*pi*x), x in [0,1)
#if __has_builtin(__builtin_amdgcn_cosf)
    return __builtin_amdgcn_cosf(x);
#else
    return cosf(x * 6.28318530717958647692f);
#endif
}
__device__ __forceinline__ float fast_exp2(float x) {
#if __has_builtin(__builtin_amdgcn_exp2f)
    return __builtin_amdgcn_exp2f(x);
#else
    return exp2f(x);
#endif
}
__device__ __forceinline__ unsigned short f2bf(float f) { // RNE f32 -> bf16 bits
    unsigned u = __float_as_uint(f);
    return (unsigned short)((u + 0x7FFFu + ((u >> 16) & 1u)) >> 16);
}
__device__ __forceinline__ float bf2f(unsigned short b) {
    return __uint_as_float(((unsigned)b) << 16);
}

constexpr int kN = 16384, kD = 8, kS = 8, kF = 1024, kR = 2048;
constexpr float kInv2Pi = 0.15915494309189535f;
constexpr float kLog2e  = 1.4426950408889634f;
// ws layout: 512 prior B-tiles then 128 update B-tiles, 64 uint4 (1KB) each.
constexpr size_t kWsNeed = (size_t)(512 + 128) * 64 * 16;

// ===========================================================================
// PREP: build MFMA B-fragments (K=32) in d_ws.
// B-frag layout (16x16x32): lane l holds B[k=(l>>4)*8+j][col=l&15], j=0..7.
// Prior tile (s,ft), col=f=ft*16+c:
//   k0..7 : bf16_hi(omega[s][d][f]*inv2pi/ls)     (pairs with x_hi)
//   k8..15: same hi                               (pairs with x_lo)
//   k16..23: bf16_lo residual                     (pairs with x_hi)
//   k24: phase_hi*inv2pi  k25: phase_lo  (pair with 1)   k26..31: 0
// Update tile rt, col=r=rt*16+c  (log2-domain exponent, L=log2e/ls^2):
//   k0..7 : bf16_hi(L*z[r][d])  k8..15: hi  k16..23: lo
//   k24: zt_hi  k25: zt_lo  (zt=-0.5*L*||z||^2, pair with 1)
//   k26,k27: 1.0 (pair with xt_hi/xt_lo from A side)   k28..31: 0
// ===========================================================================
__global__ __launch_bounds__(256)
void prep_kernel(const float* __restrict__ omega, const float* __restrict__ phase,
                 const float* __restrict__ Z, const float* __restrict__ lsp,
                 uint4* __restrict__ ws)
{
    const int job  = blockIdx.x * 256 + threadIdx.x;   // 0..40959
    const int lane = job & 63;
    const int tile = job >> 6;                          // 0..639
    const int g = lane >> 4, c = lane & 15;

    const float inv_ls = 1.0f / lsp[0];
    const float m_ang  = kInv2Pi * inv_ls;
    const float L      = kLog2e * inv_ls * inv_ls;

    unsigned short h[8];
    if (tile < 512) {
        const int s = tile >> 6, ft = tile & 63, f = ft * 16 + c;
        const float* om = omega + s * (kD * kF);
        const float* ph = phase + s * kF;
        #pragma unroll
        for (int j = 0; j < 8; ++j) {
            const int k = g * 8 + j;
            unsigned short v = 0;
            if (k < 16) {                      // omega hi (two copies)
                const int d = k & 7;
                v = f2bf(om[d * kF + f] * m_ang);
            } else if (k < 24) {               // omega lo
                const int d = k - 16;
                const float w = om[d * kF + f] * m_ang;
                v = f2bf(w - bf2f(f2bf(w)));
            } else if (k == 24) {
                v = f2bf(ph[f] * kInv2Pi);
            } else if (k == 25) {
                const float p = ph[f] * kInv2Pi;
                v = f2bf(p - bf2f(f2bf(p)));
            }
            h[j] = v;
        }
    } else {
        const int rt = tile - 512, r = rt * 16 + c;
        const float* zr = Z + r * kD;
        float zz = 0.f;
        #pragma unroll
        for (int d = 0; d < kD; ++d) zz = fmaf(zr[d], zr[d], zz);
        const float zt = -0.5f * L * zz;
        #pragma unroll
        for (int j = 0; j < 8; ++j) {
            const int k = g * 8 + j;
            unsigned short v = 0;
            if (k < 16) {
                v = f2bf(L * zr[k & 7]);
            } else if (k < 24) {
                const float w = L * zr[k - 16];
                v = f2bf(w - bf2f(f2bf(w)));
            } else if (k == 24) {
                v = f2bf(zt);
            } else if (k == 25) {
                v = f2bf(zt - bf2f(f2bf(zt)));
            } else if (k < 28) {
                v = 0x3F80;                    // 1.0 bf16
            }
            h[j] = v;
        }
    }
    uint4 w;
    w.x = (unsigned)h[0] | ((unsigned)h[1] << 16);
    w.y = (unsigned)h[2] | ((unsigned)h[3] << 16);
    w.z = (unsigned)h[4] | ((unsigned)h[5] << 16);
    w.w = (unsigned)h[6] | ((unsigned)h[7] << 16);
    ws[tile * 64 + lane] = w;
}

// ===========================================================================
// PRIOR: grid 2048 x 256thr (4 waves). block -> (s = bid&7, ngroup = bid>>3);
// wave w owns n-tile ngroup*4+w. Loop 64 f-tiles: 1 MFMA -> 4 angles/lane ->
// fract+cos+fw-fma. Butterfly over 16 f-cols, store.
// A-frag: lane l holds A[m=l&15][k=(l>>4)*8+j]: g0/g2 = x_hi, g1 = x_lo,
// g3 = {1,1,0,...} (phase rows).
// ===========================================================================
__global__ __launch_bounds__(256)
void prior_mfma(const float* __restrict__ X, const float* __restrict__ fw,
                const float* __restrict__ varp, const uint4* __restrict__ wsP,
                float* __restrict__ out)
{
    const int tid  = threadIdx.x;
    const int lane = tid & 63;
    const int wave = __builtin_amdgcn_readfirstlane(tid >> 6);
    const int s  = blockIdx.x & 7;
    const int ng = blockIdx.x >> 3;
    const int ntile = ng * 4 + wave, n0 = ntile * 16;
    const int c = lane & 15, g = lane >> 4;

    // A fragment
    float xv[kD];
    {
        const float4 x0 = *reinterpret_cast<const float4*>(X + (n0 + c) * kD);
        const float4 x1 = *reinterpret_cast<const float4*>(X + (n0 + c) * kD + 4);
        xv[0]=x0.x; xv[1]=x0.y; xv[2]=x0.z; xv[3]=x0.w;
        xv[4]=x1.x; xv[5]=x1.y; xv[6]=x1.z; xv[7]=x1.w;
    }
    bf16x8 af;
    if (g == 3) {
        #pragma unroll
        for (int j = 0; j < 8; ++j) af[j] = 0;
        af[0] = (short)0x3F80; af[1] = (short)0x3F80;
    } else if (g == 1) {
        #pragma unroll
        for (int j = 0; j < 8; ++j)
            af[j] = (short)f2bf(xv[j] - bf2f(f2bf(xv[j])));
    } else {
        #pragma unroll
        for (int j = 0; j < 8; ++j) af[j] = (short)f2bf(xv[j]);
    }

    const float scale = sqrtf(2.0f * varp[0] / (float)kF);
    const uint4* bp = wsP + (s * 64) * 64 + lane;
    const float* fwp = fw + s * kF + c;

    float a0 = 0.f, a1 = 0.f, a2 = 0.f, a3 = 0.f;
    #pragma unroll 2
    for (int ft = 0; ft < 64; ++ft) {
        const uint4 bw  = bp[ft * 64];
        const float fwv = fwp[ft * 16];
        const f32x4 dv = __builtin_amdgcn_mfma_f32_16x16x32_bf16(
            af, __builtin_bit_cast(bf16x8, bw), (f32x4){0.f, 0.f, 0.f, 0.f}, 0, 0, 0);
        a0 = fmaf(fwv, fast_cos2pi(fast_fract(dv[0])), a0);
        a1 = fmaf(fwv, fast_cos2pi(fast_fract(dv[1])), a1);
        a2 = fmaf(fwv, fast_cos2pi(fast_fract(dv[2])), a2);
        a3 = fmaf(fwv, fast_cos2pi(fast_fract(dv[3])), a3);
    }
    #pragma unroll
    for (int m = 1; m <= 8; m <<= 1) {
        a0 += __shfl_xor(a0, m); a1 += __shfl_xor(a1, m);
        a2 += __shfl_xor(a2, m); a3 += __shfl_xor(a3, m);
    }
    if (c == 0) {
        float* o = out + s * kN + n0 + g * 4;
        o[0] = scale * a0; o[1] = scale * a1; o[2] = scale * a2; o[3] = scale * a3;
    }
}

// ===========================================================================
// UPDATE: grid 1024 x 256thr. block -> n-tile; wave q owns r-tiles [q*32,q*32+32).
// Per r-tile: 1 MFMA -> log2-exponent -> min0 -> exp2 -> 8 cw-FMAs per row.
// Butterfly over 16 r-cols, atomicAdd into out (after prior's plain stores).
// A-frag g3 = {1,1,xt_hi,xt_lo,0..}.
// ===========================================================================
__global__ __launch_bounds__(256)
void update_mfma(const float* __restrict__ X, const float* __restrict__ cw,
                 const float* __restrict__ varp, const float* __restrict__ lsp,
                 const uint4* __restrict__ wsU, float* __restrict__ out)
{
    const int tid  = threadIdx.x;
    const int lane = tid & 63;
    const int q = __builtin_amdgcn_readfirstlane(tid >> 6);
    const int n0 = blockIdx.x * 16;
    const int c = lane & 15, g = lane >> 4;

    const float inv_ls = 1.0f / lsp[0];
    const float L = kLog2e * inv_ls * inv_ls;

    float xv[kD];
    {
        const float4 x0 = *reinterpret_cast<const float4*>(X + (n0 + c) * kD);
        const float4 x1 = *reinterpret_cast<const float4*>(X + (n0 + c) * kD + 4);
        xv[0]=x0.x; xv[1]=x0.y; xv[2]=x0.z; xv[3]=x0.w;
        xv[4]=x1.x; xv[5]=x1.y; xv[6]=x1.z; xv[7]=x1.w;
    }
    bf16x8 af;
    if (g == 3) {
        float xx = 0.f;
        #pragma unroll
        for (int d = 0; d < kD; ++d) xx = fmaf(xv[d], xv[d], xx);
        const float xt = -0.5f * L * xx;
        const unsigned short th = f2bf(xt);
        const unsigned short tl = f2bf(xt - bf2f(th));
        #pragma unroll
        for (int j = 0; j < 8; ++j) af[j] = 0;
        af[0] = (short)0x3F80; af[1] = (short)0x3F80;
        af[2] = (short)th;     af[3] = (short)tl;
    } else if (g == 1) {
        #pragma unroll
        for (int j = 0; j < 8; ++j)
            af[j] = (short)f2bf(xv[j] - bf2f(f2bf(xv[j])));
    } else {
        #pragma unroll
        for (int j = 0; j < 8; ++j) af[j] = (short)f2bf(xv[j]);
    }

    float acc[kS][4];
    #pragma unroll
    for (int s2 = 0; s2 < kS; ++s2)
        #pragma unroll
        for (int r = 0; r < 4; ++r) acc[s2][r] = 0.f;

    const uint4* bp = wsU + lane;
    const float* cwp = cw + c;
    const int rt0 = q * 32;
    for (int rt = rt0; rt < rt0 + 32; ++rt) {
        const uint4 bw = bp[rt * 64];
        const f32x4 dv = __builtin_amdgcn_mfma_f32_16x16x32_bf16(
            af, __builtin_bit_cast(bf16x8, bw), (f32x4){0.f, 0.f, 0.f, 0.f}, 0, 0, 0);
        float K[4];
        #pragma unroll
        for (int r = 0; r < 4; ++r) K[r] = fast_exp2(fminf(dv[r], 0.f));
        const int rb = rt * 16;
        #pragma unroll
        for (int s2 = 0; s2 < kS; ++s2) {
            const float cwv = cwp[s2 * kR + rb];
            #pragma unroll
            for (int r = 0; r < 4; ++r) acc[s2][r] = fmaf(K[r], cwv, acc[s2][r]);
        }
    }
    #pragma unroll
    for (int m = 1; m <= 8; m <<= 1)
        #pragma unroll
        for (int s2 = 0; s2 < kS; ++s2)
            #pragma unroll
            for (int r = 0; r < 4; ++r) acc[s2][r] += __shfl_xor(acc[s2][r], m);

    if (c == 0) {
        const float var = varp[0];
        #pragma unroll
        for (int s2 = 0; s2 < kS; ++s2) {
            float* o = out + s2 * kN + n0 + g * 4;
            #pragma unroll
            for (int r = 0; r < 4; ++r) atomicAdd(o + r, var * acc[s2][r]);
        }
    }
}

// ===========================================================================
// Fallback (proven round-3 kernels) if ws_size is too small for fragments.
// ===========================================================================
__global__ __launch_bounds__(512, 8)
void prior_fb(const float* __restrict__ X, const float* __restrict__ omega,
              const float* __restrict__ phase, const float* __restrict__ fw,
              const float* __restrict__ varp, const float* __restrict__ lsp,
              float* __restrict__ out)
{
    const int tid  = threadIdx.x;
    const int nloc = tid & 63;
    const int wave = __builtin_amdgcn_readfirstlane(tid >> 6);
    const int s    = blockIdx.y;
    const int n    = blockIdx.x * 64 + nloc;
    const float variance = varp[0];
    const float inv_ls   = 1.0f / lsp[0];
    const float scale = sqrtf(2.0f * variance / (float)kF);
    float xa[kD];
    {
        const float4 x0 = *reinterpret_cast<const float4*>(X + n * kD);
        const float4 x1 = *reinterpret_cast<const float4*>(X + n * kD + 4);
        const float m = inv_ls * kInv2Pi;
        xa[0]=x0.x*m; xa[1]=x0.y*m; xa[2]=x0.z*m; xa[3]=x0.w*m;
        xa[4]=x1.x*m; xa[5]=x1.y*m; xa[6]=x1.z*m; xa[7]=x1.w*m;
    }
    const float* om  = omega + s * (kD * kF);
    const float* ph  = phase + s * kF;
    const float* fwp = fw    + s * kF;
    const int f0 = wave * 128;
    float acc0 = 0.f, acc1 = 0.f;
    for (int fb = f0; fb < f0 + 128; fb += 8) {
        float cv[8];
        #pragma unroll
        for (int j = 0; j < 8; ++j) {
            float t = ph[fb + j] * kInv2Pi;
            #pragma unroll
            for (int d = 0; d < kD; ++d) t = fmaf(xa[d], om[d * kF + fb + j], t);
            cv[j] = fast_cos2pi(fast_fract(t));
        }
        #pragma unroll
        for (int j = 0; j < 8; j += 2) {
            acc0 = fmaf(fwp[fb + j], cv[j], acc0);
            acc1 = fmaf(fwp[fb + j + 1], cv[j + 1], acc1);
        }
    }
    __shared__ float red[8][64];
    red[wave][nloc] = acc0 + acc1;
    __syncthreads();
    if (tid < 64) {
        float t = 0.f;
        #pragma unroll
        for (int k = 0; k < 8; ++k) t += red[k][tid];
        out[s * kN + blockIdx.x * 64 + tid] = scale * t;
    }
}

__global__ __launch_bounds__(1024, 8)
void update_fb(const float* __restrict__ X, const float* __restrict__ Z,
               const float* __restrict__ cw, const float* __restrict__ varp,
               const float* __restrict__ lsp, float* __restrict__ out)
{
    const int tid  = threadIdx.x;
    const int nloc = tid & 63;
    const int wave = __builtin_amdgcn_readfirstlane(tid >> 6);
    const int n    = blockIdx.x * 64 + nloc;
    const float variance = varp[0];
    const float inv_ls   = 1.0f / lsp[0];
    const float L = kLog2e * inv_ls * inv_ls;
    __shared__ float zt_lds[kR];
    __shared__ float red[16][64][kS + 1];
    float x[kD];
    {
        const float4 x0 = *reinterpret_cast<const float4*>(X + n * kD);
        const float4 x1 = *reinterpret_cast<const float4*>(X + n * kD + 4);
        x[0]=x0.x; x[1]=x0.y; x[2]=x0.z; x[3]=x0.w;
        x[4]=x1.x; x[5]=x1.y; x[6]=x1.z; x[7]=x1.w;
    }
    for (int r = tid; r < kR; r += 1024) {
        const float4 z0 = *reinterpret_cast<const float4*>(Z + r * kD);
        const float4 z1 = *reinterpret_cast<const float4*>(Z + r * kD + 4);
        float z2 = z0.x*z0.x + z0.y*z0.y + z0.z*z0.z + z0.w*z0.w
                 + z1.x*z1.x + z1.y*z1.y + z1.z*z1.z + z1.w*z1.w;
        zt_lds[r] = -0.5f * L * z2;
    }
    __syncthreads();
    float xb[kD]; float x2 = 0.f;
    #pragma unroll
    for (int d = 0; d < kD; ++d) { xb[d] = x[d] * L; x2 = fmaf(x[d], x[d], x2); }
    const float xt = -0.5f * L * x2;
    float accU[2][kS];
    #pragma unroll
    for (int j = 0; j < kS; ++j) { accU[0][j] = 0.f; accU[1][j] = 0.f; }
    const int r0 = wave * 128;
    #pragma unroll 4
    for (int rr = 0; rr < 128; ++rr) {
        const int r = r0 + rr;
        float e = xt + zt_lds[r];
        #pragma unroll
        for (int d = 0; d < kD; ++d) e = fmaf(xb[d], Z[r * kD + d], e);
        e = fminf(e, 0.f);
        const float K = fast_exp2(e);
        #pragma unroll
        for (int j = 0; j < kS; ++j)
            accU[rr & 1][j] = fmaf(K, cw[j * kR + r], accU[rr & 1][j]);
    }
    #pragma unroll
    for (int j = 0; j < kS; ++j) red[wave][nloc][j] = accU[0][j] + accU[1][j];
    __syncthreads();
    if (tid < 512) {
        const int n2 = tid & 63;
        const int jj = tid >> 6;
        float tot = 0.f;
        #pragma unroll
        for (int k = 0; k < 16; ++k) tot += red[k][n2][jj];
        const int idx = jj * kN + blockIdx.x * 64 + n2;
        out[idx] = fmaf(variance, tot, out[idx]);
    }
}

extern "C" void kernel_launch(void* const* d_in, const int* in_sizes, int n_in,
                              void* d_out, int out_size, void* d_ws, size_t ws_size,
                              hipStream_t stream) {
    const float* X  = (const float*)d_in[0];
    const float* Z  = (const float*)d_in[1];
    const float* om = (const float*)d_in[2];
    const float* ph = (const float*)d_in[3];
    const float* fw = (const float*)d_in[4];
    const float* cw = (const float*)d_in[5];
    const float* vp = (const float*)d_in[6];
    const float* lp = (const float*)d_in[7];
    float* out = (float*)d_out;

    if (ws_size >= kWsNeed) {
        uint4* wsP = (uint4*)d_ws;
        uint4* wsU = wsP + (size_t)512 * 64;
        hipLaunchKernelGGL(prep_kernel, dim3(160), dim3(256), 0, stream,
                           om, ph, Z, lp, wsP);
        hipLaunchKernelGGL(prior_mfma, dim3(2048), dim3(256), 0, stream,
                           X, fw, vp, wsP, out);
        hipLaunchKernelGGL(update_mfma, dim3(1024), dim3(256), 0, stream,
                           X, cw, vp, lp, wsU, out);
    } else {
        hipLaunchKernelGGL(prior_fb, dim3(kN / 64, kS), dim3(512), 0, stream,
                           X, om, ph, fw, vp, lp, out);
        hipLaunchKernelGGL(update_fb, dim3(kN / 64), dim3(1024), 0, stream,
                           X, Z, cw, vp, lp, out);
    }
}